// Round 9
// baseline (178.175 us; speedup 1.0000x reference)
//
#include <hip/hip_runtime.h>
#include <hip/hip_fp16.h>

#define N_NODES 10000
#define BATCH   8
#define IN_SZ   64
#define UNITS   64
#define ROW_U   256            // uints per f16 row (512 f16 = 4 stripes of 64)
#define RCAP    96             // fixed per-row edge capacity (P(deg>96) ~ 1e-18)
#define STR     (N_NODES * 64) // uints per stripe (640,000)

typedef unsigned int uint;
typedef unsigned short ushort;
typedef __attribute__((ext_vector_type(8))) _Float16 half8;
typedef __attribute__((ext_vector_type(4))) float float4v;
typedef __attribute__((ext_vector_type(2))) float float2v;

// ---- numeric helpers -------------------------------------------------------
// Edge values bf16-packed (high 16 bits ARE the fp32 bits -> SALU decode).
__device__ inline uint f2bf_bits(float f) {
    uint u = __float_as_uint(f);
    uint r = ((u >> 16) & 1u) + 0x7FFFu;
    return (u + r) >> 16;
}
// x tensors stored as packed fp16 (RNE): enables v_fma_mix_f32 in spmm loop.
__device__ inline uint pack2h(float a, float b) {
    return (uint)__half_as_ushort(__float2half(a)) |
           ((uint)__half_as_ushort(__float2half(b)) << 16);
}
__device__ inline float h_lo(uint u) {
    return __half2float(__ushort_as_half((ushort)(u & 0xFFFFu)));
}
__device__ inline float h_hi(uint u) {
    return __half2float(__ushort_as_half((ushort)(u >> 16)));
}

// ---------------------------------------------------------------------------
// EVIDENCE LEDGER (r1..r8):
//   K = 106.3us, F = 75.1us fixed harness       [r1 vs r5 double-pipeline]
//   t_spmm(s_load) + c = 25.3us                 [r6 x5 repeat]
//   readlane edge path: -3.2us per spmm         [r8: 181.35 -> 174.93]
//   Fusion/persistent: TLP collapse, loses      [r3, r7]
//   ALGEBRA (r1,r5,r6,r7 + fused dur 53.2 measured): t_C ~= 24us
//     INDEPENDENT of per-dispatch gap c. Combine is 3-4x its traffic model.
//   Cause: per-block W staging (48 it/thread, int-div-by-3, [64][200] tile
//   -> 100-dword row stride -> 8-way LDS bank conflicts on BOTH ds_write and
//   ds_read_b128; r7 logged 1.24M SQ_LDS_BANK_CONFLICT).
//   THIS ROUND: prepack W once (in transpose) into fragment-linear
//   wt[u*192 + m*64 + i] f16; combine reads B-fragments directly from the
//   L2-resident 24KB table. LDS/syncthreads/div deleted from combine.
// ---------------------------------------------------------------------------

// ---------------------------------------------------------------------------
// k_transpose_scatter: r1 body + one-time W prepack (first 12288 threads).
// Grid <<<N_NODES, 256>>>.
// ---------------------------------------------------------------------------
__global__ __launch_bounds__(256) void k_transpose_scatter(
    const float2v* __restrict__ in2, uint* __restrict__ x0,
    const int* __restrict__ rows, const int* __restrict__ cols,
    const float* __restrict__ vals, int* __restrict__ cursor,
    uint* __restrict__ edges, const float* __restrict__ W,
    ushort* __restrict__ wt, int nnz) {
    int gid = blockIdx.x * 256 + threadIdx.x;      // 2,560,000 total
    if (gid < nnz) {
        int r   = rows[gid];
        int pos = r * RCAP + atomicAdd(&cursor[r], 1);
        edges[pos] = (uint)cols[gid] | (f2bf_bits(vals[gid]) << 16);
    }
    if (gid < 192 * 64) {               // one-time W prepack (once, not 1256x)
        int f = gid >> 6, u = gid & 63;
        int i = f / 3, m = f - 3 * i;
        wt[(size_t)u * 192 + m * 64 + i] =
            (ushort)__half_as_ushort(__float2half(W[gid]));
    }
    int n  = gid >> 8;          // node
    int b  = (gid >> 5) & 7;    // batch
    int iu = gid & 31;
    float2v v = __builtin_nontemporal_load(&in2[(size_t)b * (N_NODES * 32) +
                                                (size_t)n * 32 + iu]);
    int q = (gid >> 6) & 3;     // stripe
    x0[(size_t)q * STR + (size_t)n * 64 + (gid & 63)] = pack2h(v.x, v.y);
}

// ---- spmm inner machinery (r8, proven) -------------------------------------
#define READE(EP, KB)                                                         \
    {                                                                         \
        uint _es = ((KB) < 8) ? erec : erec2;                                 \
        int  _i0 = (((KB) * 8) & 63);                                         \
        _Pragma("unroll") for (int jj = 0; jj < 8; ++jj)                      \
            EP[jj] = __builtin_amdgcn_readlane(_es, _i0 + jj);                \
    }

#define GATHERX(XR, EP)                                                       \
    _Pragma("unroll") for (int jj = 0; jj < 8; ++jj) {                        \
        uint c = EP[jj] & 0x3FFFu;                                            \
        if (c > N_NODES - 1) c = N_NODES - 1; /* s_min (garbage slots) */     \
        XR[jj] = xq[c * 64u + lane];          /* SALU idx + saddr gather */   \
    }

#define FMA8(EP, XR)                                                          \
    _Pragma("unroll") for (int jj = 0; jj < 8; ++jj) {                        \
        float vj = __uint_as_float(EP[jj] & 0xFFFF0000u); /* SALU decode */   \
        a0 += vj * h_lo(XR[jj]); /* v_fma_mix_f32 */                          \
        a1 += vj * h_hi(XR[jj]); /* v_fma_mix_f32 */                          \
    }

// ---------------------------------------------------------------------------
// k_spmm: UNCHANGED r8 body (readlane edge path). Grid <<<N_NODES, 256>>>.
// ---------------------------------------------------------------------------
__global__ __launch_bounds__(256) void k_spmm(const int* __restrict__ cursor,
                                              const uint* __restrict__ edges,
                                              const uint* __restrict__ xin,
                                              uint* __restrict__ xout,
                                              const uint* __restrict__ xsub,
                                              float scale) {
    int L    = blockIdx.x;              // 10000 blocks
    int q    = (L & 7) >> 1;            // stripe pinned to XCD pair {2q,2q+1}
    int rb   = ((L >> 3) << 1) | (L & 1);   // 0..2499, bijective per stripe
    int wave = threadIdx.x >> 6;
    uint lane = threadIdx.x & 63;
    int row  = rb * 4 + wave;

    const uint* xq = xin + (size_t)q * STR;
    int base = row * RCAP;
    int cnt  = __builtin_amdgcn_readfirstlane(cursor[row]);
    int nblk = (cnt + 7) >> 3;          // >= 1 (diagonal guarantees cnt >= 1)

    uint erec = edges[base + (int)lane];
    if ((int)lane >= cnt) erec &= 0x3FFFu;          // v_cndmask
    uint erec2 = 0;
    if (cnt > 64) {                                  // uniform branch, rare
        erec2 = edges[base + 64 + (int)lane];
        if ((int)lane + 64 >= cnt) erec2 &= 0x3FFFu;
    }

    uint sx = 0;
    if (xsub) sx = __builtin_nontemporal_load(
        &xsub[(size_t)q * STR + (size_t)row * 64 + lane]);

    float a0 = 0.f, a1 = 0.f;
    uint epA[8], epB[8], xA[8], xB[8];
    READE(epA, 0);
    GATHERX(xA, epA);
    int k = 0;
    for (; k + 2 <= nblk; k += 2) {
        READE(epB, k + 1);                // register-only: no lgkm chain
        GATHERX(xB, epB);                 // gathers in flight
        FMA8(epA, xA);                    // consume stage k
        if (k + 2 < nblk) {
            READE(epA, k + 2);
            GATHERX(xA, epA);
        }
        FMA8(epB, xB);                    // consume stage k+1
    }
    if (k < nblk) FMA8(epA, xA);          // odd block count

    float o0 = scale * a0, o1 = scale * a1;
    if (xsub) {
        o0 -= h_lo(sx);
        o1 -= h_hi(sx);
    }
    __builtin_nontemporal_store(pack2h(o0, o1),
        &xout[(size_t)q * STR + (size_t)row * 64 + lane]);
}

// ---------------------------------------------------------------------------
// k_combine (MFMA f16, NO LDS): B-fragments read directly from prepacked
// wt[u*192 + k] (24KB, L2-resident broadcast). Per thread: 6 af loads,
// 24 bf loads (16B aligned: byte off = 384*(ut*16+mrow) + 2*(kb*32+quad*8)),
// 24 MFMA, 16 stores. No staging loop, no syncthreads, no bank conflicts.
// Grid <<<157*8, 256>>>; b = L&7 pins batch -> stripe q=b>>1 on XCD pair.
// ---------------------------------------------------------------------------
__global__ __launch_bounds__(256) void k_combine(const uint* __restrict__ x0,
                                                 const uint* __restrict__ x1,
                                                 const uint* __restrict__ x2,
                                                 const ushort* __restrict__ wt,
                                                 const float* __restrict__ bias,
                                                 float* __restrict__ out) {
    int t = threadIdx.x;
    int wave = t >> 6, lane = t & 63;
    int mrow = lane & 15, quad = lane >> 4;
    int L    = blockIdx.x;
    int b    = L & 7;                  // XCD-pinned batch -> stripe b>>1
    int n0   = (L >> 3) * 64 + wave * 16;

    const uint* xs[3] = {x0, x1, x2};
    int an = n0 + mrow;
    if (an > N_NODES - 1) an = N_NODES - 1;    // clamp tail reads

    half8 af[6];
#pragma unroll
    for (int kb = 0; kb < 6; ++kb) {
        int mat = kb >> 1;
        int c_u = b * 32 + (kb & 1) * 16 + quad * 4;      // column uint index
        int q   = c_u >> 6;                               // = b>>1
        af[kb] = __builtin_nontemporal_load(
            (const half8*)(xs[mat] + (size_t)q * STR + (size_t)an * 64 +
                           (c_u & 63)));
    }

    float4v acc[4];
#pragma unroll
    for (int ut = 0; ut < 4; ++ut) acc[ut] = (float4v){0.f, 0.f, 0.f, 0.f};

#pragma unroll
    for (int kb = 0; kb < 6; ++kb)
#pragma unroll
        for (int ut = 0; ut < 4; ++ut) {
            half8 bf = *(const half8*)&wt[(size_t)(ut * 16 + mrow) * 192 +
                                          kb * 32 + quad * 8];
            acc[ut] = __builtin_amdgcn_mfma_f32_16x16x32_f16(
                af[kb], bf, acc[ut], 0, 0, 0);
        }

#pragma unroll
    for (int ut = 0; ut < 4; ++ut) {
        float bv = bias[ut * 16 + mrow];
        int u = ut * 16 + mrow;
#pragma unroll
        for (int r = 0; r < 4; ++r) {
            int n = n0 + quad * 4 + r;
            if (n < N_NODES)
                __builtin_nontemporal_store(acc[ut][r] + bv,
                    &out[((size_t)b * N_NODES + n) * UNITS + u]);
        }
    }
}

// ---------------------------------------------------------------------------
extern "C" void kernel_launch(void* const* d_in, const int* in_sizes, int n_in,
                              void* d_out, int out_size, void* d_ws, size_t ws_size,
                              hipStream_t stream) {
    const float* inputs = (const float*)d_in[0];
    const int*   rows   = (const int*)d_in[1];
    const int*   cols   = (const int*)d_in[2];
    const float* vals   = (const float*)d_in[3];
    const float* W      = (const float*)d_in[4];
    const float* bias   = (const float*)d_in[5];
    float*       out    = (float*)d_out;
    int nnz = in_sizes[1];

    char* p = (char*)d_ws;
    auto alloc = [&](size_t bytes) {
        char* r = p;
        p += (bytes + 255) & ~(size_t)255;
        return r;
    };
    uint*   x0     = (uint*)alloc(sizeof(uint) * (size_t)N_NODES * ROW_U);
    uint*   x1     = (uint*)alloc(sizeof(uint) * (size_t)N_NODES * ROW_U);
    uint*   x2     = (uint*)alloc(sizeof(uint) * (size_t)N_NODES * ROW_U);
    int*    cursor = (int*)alloc(sizeof(int) * N_NODES);
    // +128 uints pad: erec2 read (base+64+lane) of the last row stays in-bounds
    uint*   edges  = (uint*)alloc(sizeof(uint) * ((size_t)N_NODES * RCAP + 128));
    ushort* wt     = (ushort*)alloc(sizeof(ushort) * 192 * 64);   // 24 KB

    (void)hipMemsetAsync(cursor, 0, sizeof(int) * N_NODES, stream);
    k_transpose_scatter<<<N_NODES, 256, 0, stream>>>(
        (const float2v*)inputs, x0, rows, cols, vals, cursor, edges, W, wt,
        nnz);
    k_spmm<<<N_NODES, 256, 0, stream>>>(cursor, edges, x0, x1, nullptr, 1.0f);
    k_spmm<<<N_NODES, 256, 0, stream>>>(cursor, edges, x1, x2, x0, 2.0f);
    k_combine<<<157 * 8, 256, 0, stream>>>(x0, x1, x2, wt, bias, out);
}